// Round 5
// baseline (4615.285 us; speedup 1.0000x reference)
//
#include <hip/hip_runtime.h>
#include <stdint.h>
#include <math.h>

#define NN 50000
#define NE 800000

typedef __attribute__((ext_vector_type(8))) __bf16 bf16x8;
typedef __attribute__((ext_vector_type(8))) unsigned short u16x8;
typedef __attribute__((ext_vector_type(4))) float f32x4;
typedef unsigned int uint32;

// ---------------------------------------------------------------------------
// One-time CSR build: histogram -> exclusive scan -> scatter (src only).
// ---------------------------------------------------------------------------
__global__ void hist_k(const int* __restrict__ dst, int* __restrict__ hist) {
    int e = blockIdx.x * 256 + threadIdx.x;
    if (e < NE) atomicAdd(&hist[dst[e]], 1);
}

__global__ void scan_k(const int* __restrict__ hist, int* __restrict__ row_off) {
    __shared__ int lds[1024];
    const int tid = threadIdx.x;
    int carry = 0;
    for (int base = 0; base < NN; base += 1024) {
        int i = base + tid;
        int v = (i < NN) ? hist[i] : 0;
        lds[tid] = v;
        __syncthreads();
        #pragma unroll
        for (int s = 1; s < 1024; s <<= 1) {
            int add = (tid >= s) ? lds[tid - s] : 0;
            __syncthreads();
            lds[tid] += add;
            __syncthreads();
        }
        int incl = lds[tid];
        if (i < NN) row_off[i] = carry + incl - v;   // exclusive
        carry += lds[1023];
        __syncthreads();
    }
    if (tid == 0) row_off[NN] = carry;               // == NE
}

__global__ void copy_k(const int* __restrict__ a, int* __restrict__ b, int n) {
    int i = blockIdx.x * 256 + threadIdx.x;
    if (i < n) b[i] = a[i];
}

__global__ void scatter_k(const int* __restrict__ src, const int* __restrict__ dst,
                          int* __restrict__ cnt, int* __restrict__ s_src) {
    int e = blockIdx.x * 256 + threadIdx.x;
    if (e < NE) {
        int d = dst[e];
        int p = atomicAdd(&cnt[d], 1);
        s_src[p] = src[e];
    }
}

// ---------------------------------------------------------------------------
// Node transform: u = y @ (W1a - W1b) + b1 ; v = y @ W1b   (fp32 VALU)
// ---------------------------------------------------------------------------
template<int CIN, int COUT, bool FIRST>
__global__ void node_transform(const float* __restrict__ xin,
                               const float* __restrict__ ain,
                               const float* __restrict__ b2p,
                               const float* __restrict__ W1,
                               const float* __restrict__ b1,
                               float* __restrict__ U,
                               float* __restrict__ Vv)
{
    __shared__ float ylds[32][CIN];
    const int nbase = blockIdx.x * 32;
    const int tid = threadIdx.x;

    for (int idx = tid; idx < 32 * CIN; idx += COUT) {
        int nn = idx / CIN, k = idx - nn * CIN;
        int n = nbase + nn;
        float val = 0.f;
        if (n < NN) {
            if (FIRST) {
                val = xin[(size_t)n * CIN + k];
            } else {
                float a = ain[(size_t)n * CIN + k];
                val = fmaxf(a + b2p[k], 0.f);   // -inf sentinel -> 0
            }
        }
        ylds[nn][k] = val;
    }
    __syncthreads();

    const int j = tid;
    float ua[32], va[32];
    #pragma unroll
    for (int t = 0; t < 32; ++t) { ua[t] = 0.f; va[t] = 0.f; }

    for (int k4 = 0; k4 < CIN / 4; ++k4) {
        float wd[4], wb[4];
        #pragma unroll
        for (int i = 0; i < 4; ++i) {
            float a = W1[(size_t)(k4 * 4 + i) * COUT + j];
            float b = W1[(size_t)(CIN + k4 * 4 + i) * COUT + j];
            wb[i] = b;
            wd[i] = a - b;
        }
        #pragma unroll
        for (int t = 0; t < 32; ++t) {
            const float4 y4 = *reinterpret_cast<const float4*>(&ylds[t][k4 * 4]);
            ua[t] = fmaf(y4.x, wd[0], ua[t]);
            ua[t] = fmaf(y4.y, wd[1], ua[t]);
            ua[t] = fmaf(y4.z, wd[2], ua[t]);
            ua[t] = fmaf(y4.w, wd[3], ua[t]);
            va[t] = fmaf(y4.x, wb[0], va[t]);
            va[t] = fmaf(y4.y, wb[1], va[t]);
            va[t] = fmaf(y4.z, wb[2], va[t]);
            va[t] = fmaf(y4.w, wb[3], va[t]);
        }
    }

    const float bj = b1[j];
    for (int t = 0; t < 32; ++t) {
        int n = nbase + t;
        if (n < NN) {
            U [(size_t)n * COUT + j] = ua[t] + bj;
            Vv[(size_t)n * COUT + j] = va[t];
        }
    }
}

// ---------------------------------------------------------------------------
// W2 -> MFMA B-fragment prep (hi/lo bf16 split), fragment-packed layout.
// frag = nt*KS + ks; lane l holds W2[ks*32 + (l>>4)*8 + m][nt*16 + (l&15)],
// m=0..7, packed as 8 ushort at F[(frag*64+lane)*8].  (HW-verified round 4.)
// ---------------------------------------------------------------------------
template<int COUT>
__global__ void w2frag_prep(const float* __restrict__ W2,
                            unsigned short* __restrict__ Fhi,
                            unsigned short* __restrict__ Flo)
{
    constexpr int KS = COUT / 32;
    constexpr int NT = COUT / 16;
    int t = blockIdx.x * 256 + threadIdx.x;
    if (t >= NT * KS * 64) return;
    int frag = t >> 6, lane = t & 63;
    int ks = frag % KS, nt = frag / KS;
    int col = nt * 16 + (lane & 15);
    int k0 = ks * 32 + (lane >> 4) * 8;
    unsigned short h8[8], l8[8];
    #pragma unroll
    for (int m = 0; m < 8; ++m) {
        float w = W2[(size_t)(k0 + m) * COUT + col];
        __bf16 hb = (__bf16)w;
        float hf = (float)hb;
        __bf16 lb = (__bf16)(w - hf);
        h8[m] = __builtin_bit_cast(unsigned short, hb);
        l8[m] = __builtin_bit_cast(unsigned short, lb);
    }
    size_t base = (size_t)t * 8;
    #pragma unroll
    for (int m = 0; m < 8; ++m) { Fhi[base + m] = h8[m]; Flo[base + m] = l8[m]; }
}

// ---------------------------------------------------------------------------
// MFMA edge kernel, direct-gather A. One wave per dst node; 16-edge passes.
// Lane role: arow = lane&15 (edge row), akc = lane>>4 (k-chunk in K=32 step).
// Per pass, per ks: lane loads ITS 8-float V chunk (4-lane groups form
// contiguous 128B per row), t = relu(u+v) split to bf16 hi/lo in REGISTERS
// (no t LDS, nothing persistent to spill). B hi+lo streamed from LDS
// (frag-packed, lane-contiguous b128 -> conflict-free).
// Block = 512 = 8 nodes; LDS = 64KB (COUT=128) -> 2 blocks/CU.
// ---------------------------------------------------------------------------
static __device__ __forceinline__ void split8(const float* t, bf16x8& hi, bf16x8& lo) {
    u16x8 h, l;
    #pragma unroll
    for (int i = 0; i < 8; ++i) {
        __bf16 hb = (__bf16)t[i];
        float hf = (float)hb;
        __bf16 lb = (__bf16)(t[i] - hf);
        h[i] = __builtin_bit_cast(unsigned short, hb);
        l[i] = __builtin_bit_cast(unsigned short, lb);
    }
    hi = __builtin_bit_cast(bf16x8, h);
    lo = __builtin_bit_cast(bf16x8, l);
}

template<int COUT>
__global__ void __launch_bounds__(512, 4) edge_node_mfma(
    const float* __restrict__ U, const float* __restrict__ Vv,
    const int* __restrict__ s_src, const int* __restrict__ row_off,
    const unsigned short* __restrict__ Fhi, const unsigned short* __restrict__ Flo,
    float* __restrict__ agg)
{
    constexpr int KS = COUT / 32;          // MFMA K-steps (4 / 2)
    constexpr int NT = COUT / 16;          // output col tiles (8 / 4)
    constexpr int NFRAG = KS * NT;

    __shared__ unsigned short w2hi[NFRAG * 512];
    __shared__ unsigned short w2lo[NFRAG * 512];

    const int tid = threadIdx.x;
    for (int i = tid; i < NFRAG * 64; i += 512) {
        *reinterpret_cast<u16x8*>(&w2hi[i * 8]) =
            *reinterpret_cast<const u16x8*>(&Fhi[(size_t)i * 8]);
        *reinterpret_cast<u16x8*>(&w2lo[i * 8]) =
            *reinterpret_cast<const u16x8*>(&Flo[(size_t)i * 8]);
    }
    __syncthreads();   // no block syncs after this

    const int wave = tid >> 6, lane = tid & 63;
    const int arow = lane & 15;            // A row (edge within tile)
    const int akc  = lane >> 4;            // k-chunk within K-step

    const int n = blockIdx.x * 8 + wave;   // grid = NN/8 exactly
    const int off0 = row_off[n];
    const int deg  = row_off[n + 1] - off0;

    // U chunks this lane needs (register-resident, per node)
    float4 ua[KS], ub[KS];
    #pragma unroll
    for (int ks = 0; ks < KS; ++ks) {
        const float* up = &U[(size_t)n * COUT + (size_t)(ks * 4 + akc) * 8];
        ua[ks] = *reinterpret_cast<const float4*>(up);
        ub[ks] = *reinterpret_cast<const float4*>(up + 4);
    }

    float nmax[NT];
    #pragma unroll
    for (int nt = 0; nt < NT; ++nt) nmax[nt] = -INFINITY;

    for (int pb = 0; pb < deg; pb += 16) {
        const bool valid = (pb + arow) < deg;
        const int sv = valid ? s_src[off0 + pb + arow] : 0;
        const float* vrow = &Vv[(size_t)sv * COUT];
        const float vm = valid ? 1.f : 0.f;   // mask pad rows to t=0

        f32x4 acc[NT];
        #pragma unroll
        for (int nt = 0; nt < NT; ++nt) acc[nt] = f32x4{0.f, 0.f, 0.f, 0.f};

        // double-buffered per-ks V chunk
        float4 va = *reinterpret_cast<const float4*>(vrow + (size_t)akc * 8);
        float4 vb = *reinterpret_cast<const float4*>(vrow + (size_t)akc * 8 + 4);

        #pragma unroll
        for (int ks = 0; ks < KS; ++ks) {
            float4 na, nb;
            if (ks + 1 < KS) {
                const float* vp = vrow + (size_t)((ks + 1) * 4 + akc) * 8;
                na = *reinterpret_cast<const float4*>(vp);
                nb = *reinterpret_cast<const float4*>(vp + 4);
            }
            float t8[8];
            t8[0] = vm * fmaxf(ua[ks].x + va.x, 0.f);
            t8[1] = vm * fmaxf(ua[ks].y + va.y, 0.f);
            t8[2] = vm * fmaxf(ua[ks].z + va.z, 0.f);
            t8[3] = vm * fmaxf(ua[ks].w + va.w, 0.f);
            t8[4] = vm * fmaxf(ub[ks].x + vb.x, 0.f);
            t8[5] = vm * fmaxf(ub[ks].y + vb.y, 0.f);
            t8[6] = vm * fmaxf(ub[ks].z + vb.z, 0.f);
            t8[7] = vm * fmaxf(ub[ks].w + vb.w, 0.f);
            bf16x8 ahi, alo;
            split8(t8, ahi, alo);

            #pragma unroll
            for (int nt = 0; nt < NT; ++nt) {
                const size_t fb = (size_t)((nt * KS + ks) * 64 + lane) * 8;
                bf16x8 bhi = __builtin_bit_cast(bf16x8,
                    *reinterpret_cast<const u16x8*>(&w2hi[fb]));
                bf16x8 blo = __builtin_bit_cast(bf16x8,
                    *reinterpret_cast<const u16x8*>(&w2lo[fb]));
                acc[nt] = __builtin_amdgcn_mfma_f32_16x16x32_bf16(ahi, bhi, acc[nt], 0, 0, 0);
                acc[nt] = __builtin_amdgcn_mfma_f32_16x16x32_bf16(ahi, blo, acc[nt], 0, 0, 0);
                acc[nt] = __builtin_amdgcn_mfma_f32_16x16x32_bf16(alo, bhi, acc[nt], 0, 0, 0);
            }
            va = na; vb = nb;
        }

        // masked max over this pass (D: row = akc*4 + r, col = nt*16 + (lane&15))
        #pragma unroll
        for (int nt = 0; nt < NT; ++nt) {
            float m4 = -INFINITY;
            #pragma unroll
            for (int r = 0; r < 4; ++r) {
                int e = akc * 4 + r;
                if (pb + e < deg) m4 = fmaxf(m4, acc[nt][r]);
            }
            m4 = fmaxf(m4, __shfl_xor(m4, 16, 64));
            m4 = fmaxf(m4, __shfl_xor(m4, 32, 64));
            nmax[nt] = fmaxf(nmax[nt], m4);
        }
    }

    // direct store; deg==0 leaves -inf sentinel
    if (lane < 16) {
        #pragma unroll
        for (int nt = 0; nt < NT; ++nt)
            agg[(size_t)n * COUT + nt * 16 + lane] = nmax[nt];
    }
}

__global__ void finalize_k(const float* __restrict__ agg,
                           const float* __restrict__ b2,
                           float* __restrict__ out) {
    int i = blockIdx.x * 256 + threadIdx.x;
    if (i < NN * 128) {
        float a = agg[i];
        out[i] = (a == -INFINITY) ? 0.f : a + b2[i & 127];
    }
}

// ---------------------------------------------------------------------------
extern "C" void kernel_launch(void* const* d_in, const int* in_sizes, int n_in,
                              void* d_out, int out_size, void* d_ws, size_t ws_size,
                              hipStream_t stream)
{
    const float* x  = (const float*)d_in[0];
    const int*   ei = (const int*)d_in[1];
    const int* src = ei;          // edge_index[0]
    const int* dst = ei + NE;     // edge_index[1]

    const float *W1[4], *B1[4], *W2[4], *B2[4];
    for (int i = 0; i < 4; ++i) {
        W1[i] = (const float*)d_in[2 + 4 * i];
        B1[i] = (const float*)d_in[3 + 4 * i];
        W2[i] = (const float*)d_in[4 + 4 * i];
        B2[i] = (const float*)d_in[5 + 4 * i];
    }

    float* U   = (float*)d_ws;
    float* V   = U   + (size_t)NN * 128;
    float* agg = V   + (size_t)NN * 128;
    int* row_off = (int*)(agg + (size_t)NN * 128);   // NN+16 ints (padded)
    int* cnt     = row_off + (NN + 16);              // NN+16 ints
    int* s_src   = cnt + (NN + 16);                  // NE ints
    unsigned short* fbase = (unsigned short*)(s_src + NE);
    unsigned short *FH[4], *FL[4];
    for (int i = 0; i < 4; ++i) {
        FH[i] = fbase + (size_t)i * 32768;
        FL[i] = FH[i] + 16384;
    }

    float* out = (float*)d_out;

    // ---- one-time CSR build ----
    (void)hipMemsetAsync(cnt, 0, (size_t)NN * sizeof(int), stream);
    hipLaunchKernelGGL(hist_k, dim3((NE + 255) / 256), dim3(256), 0, stream, dst, cnt);
    hipLaunchKernelGGL(scan_k, dim3(1), dim3(1024), 0, stream, cnt, row_off);
    hipLaunchKernelGGL(copy_k, dim3((NN + 255) / 256), dim3(256), 0, stream, row_off, cnt, NN);
    hipLaunchKernelGGL(scatter_k, dim3((NE + 255) / 256), dim3(256), 0, stream, src, dst, cnt, s_src);

    // ---- W2 fragment prep (hi/lo bf16 split), all 4 layers ----
    hipLaunchKernelGGL((w2frag_prep<64>),  dim3(2), dim3(256), 0, stream, W2[0], FH[0], FL[0]);
    hipLaunchKernelGGL((w2frag_prep<128>), dim3(8), dim3(256), 0, stream, W2[1], FH[1], FL[1]);
    hipLaunchKernelGGL((w2frag_prep<128>), dim3(8), dim3(256), 0, stream, W2[2], FH[2], FL[2]);
    hipLaunchKernelGGL((w2frag_prep<128>), dim3(8), dim3(256), 0, stream, W2[3], FH[3], FL[3]);

    const int nblkA = (NN + 31) / 32;
    const int nblkE = NN / 8;      // 6250

    // ---- layer 0: 32 -> 64 ----
    hipLaunchKernelGGL((node_transform<32, 64, true>), dim3(nblkA), dim3(64), 0, stream,
                       x, nullptr, nullptr, W1[0], B1[0], U, V);
    hipLaunchKernelGGL((edge_node_mfma<64>), dim3(nblkE), dim3(512), 0, stream,
                       U, V, s_src, row_off, FH[0], FL[0], agg);

    // ---- layer 1: 64 -> 128 ----
    hipLaunchKernelGGL((node_transform<64, 128, false>), dim3(nblkA), dim3(128), 0, stream,
                       nullptr, agg, B2[0], W1[1], B1[1], U, V);
    hipLaunchKernelGGL((edge_node_mfma<128>), dim3(nblkE), dim3(512), 0, stream,
                       U, V, s_src, row_off, FH[1], FL[1], agg);

    // ---- layer 2: 128 -> 128 ----
    hipLaunchKernelGGL((node_transform<128, 128, false>), dim3(nblkA), dim3(128), 0, stream,
                       nullptr, agg, B2[1], W1[2], B1[2], U, V);
    hipLaunchKernelGGL((edge_node_mfma<128>), dim3(nblkE), dim3(512), 0, stream,
                       U, V, s_src, row_off, FH[2], FL[2], agg);

    // ---- layer 3: 128 -> 128 ----
    hipLaunchKernelGGL((node_transform<128, 128, false>), dim3(nblkA), dim3(128), 0, stream,
                       nullptr, agg, B2[2], W1[3], B1[3], U, V);
    hipLaunchKernelGGL((edge_node_mfma<128>), dim3(nblkE), dim3(512), 0, stream,
                       U, V, s_src, row_off, FH[3], FL[3], agg);

    // ---- finalize: +b2_3, empty -> 0 ----
    hipLaunchKernelGGL(finalize_k, dim3((NN * 128 + 255) / 256), dim3(256), 0, stream,
                       agg, B2[3], out);
}

// Round 6
// 2288.212 us; speedup vs baseline: 2.0170x; 2.0170x over previous
//
#include <hip/hip_runtime.h>
#include <stdint.h>
#include <math.h>

#define NN 50000
#define NE 800000

typedef __attribute__((ext_vector_type(8))) __bf16 bf16x8;
typedef __attribute__((ext_vector_type(8))) unsigned short u16x8;
typedef __attribute__((ext_vector_type(4))) float f32x4;
typedef unsigned int uint32;

// ---------------------------------------------------------------------------
// One-time CSR build: histogram -> exclusive scan -> scatter (src only).
// ---------------------------------------------------------------------------
__global__ void hist_k(const int* __restrict__ dst, int* __restrict__ hist) {
    int e = blockIdx.x * 256 + threadIdx.x;
    if (e < NE) atomicAdd(&hist[dst[e]], 1);
}

__global__ void scan_k(const int* __restrict__ hist, int* __restrict__ row_off) {
    __shared__ int lds[1024];
    const int tid = threadIdx.x;
    int carry = 0;
    for (int base = 0; base < NN; base += 1024) {
        int i = base + tid;
        int v = (i < NN) ? hist[i] : 0;
        lds[tid] = v;
        __syncthreads();
        #pragma unroll
        for (int s = 1; s < 1024; s <<= 1) {
            int add = (tid >= s) ? lds[tid - s] : 0;
            __syncthreads();
            lds[tid] += add;
            __syncthreads();
        }
        int incl = lds[tid];
        if (i < NN) row_off[i] = carry + incl - v;   // exclusive
        carry += lds[1023];
        __syncthreads();
    }
    if (tid == 0) row_off[NN] = carry;               // == NE
}

__global__ void copy_k(const int* __restrict__ a, int* __restrict__ b, int n) {
    int i = blockIdx.x * 256 + threadIdx.x;
    if (i < n) b[i] = a[i];
}

__global__ void scatter_k(const int* __restrict__ src, const int* __restrict__ dst,
                          int* __restrict__ cnt, int* __restrict__ s_src) {
    int e = blockIdx.x * 256 + threadIdx.x;
    if (e < NE) {
        int d = dst[e];
        int p = atomicAdd(&cnt[d], 1);
        s_src[p] = src[e];
    }
}

// ---------------------------------------------------------------------------
// Node transform: u = y @ (W1a - W1b) + b1 ; v = y @ W1b   (fp32 VALU)
// ---------------------------------------------------------------------------
template<int CIN, int COUT, bool FIRST>
__global__ void node_transform(const float* __restrict__ xin,
                               const float* __restrict__ ain,
                               const float* __restrict__ b2p,
                               const float* __restrict__ W1,
                               const float* __restrict__ b1,
                               float* __restrict__ U,
                               float* __restrict__ Vv)
{
    __shared__ float ylds[32][CIN];
    const int nbase = blockIdx.x * 32;
    const int tid = threadIdx.x;

    for (int idx = tid; idx < 32 * CIN; idx += COUT) {
        int nn = idx / CIN, k = idx - nn * CIN;
        int n = nbase + nn;
        float val = 0.f;
        if (n < NN) {
            if (FIRST) {
                val = xin[(size_t)n * CIN + k];
            } else {
                float a = ain[(size_t)n * CIN + k];
                val = fmaxf(a + b2p[k], 0.f);   // -inf sentinel -> 0
            }
        }
        ylds[nn][k] = val;
    }
    __syncthreads();

    const int j = tid;
    float ua[32], va[32];
    #pragma unroll
    for (int t = 0; t < 32; ++t) { ua[t] = 0.f; va[t] = 0.f; }

    for (int k4 = 0; k4 < CIN / 4; ++k4) {
        float wd[4], wb[4];
        #pragma unroll
        for (int i = 0; i < 4; ++i) {
            float a = W1[(size_t)(k4 * 4 + i) * COUT + j];
            float b = W1[(size_t)(CIN + k4 * 4 + i) * COUT + j];
            wb[i] = b;
            wd[i] = a - b;
        }
        #pragma unroll
        for (int t = 0; t < 32; ++t) {
            const float4 y4 = *reinterpret_cast<const float4*>(&ylds[t][k4 * 4]);
            ua[t] = fmaf(y4.x, wd[0], ua[t]);
            ua[t] = fmaf(y4.y, wd[1], ua[t]);
            ua[t] = fmaf(y4.z, wd[2], ua[t]);
            ua[t] = fmaf(y4.w, wd[3], ua[t]);
            va[t] = fmaf(y4.x, wb[0], va[t]);
            va[t] = fmaf(y4.y, wb[1], va[t]);
            va[t] = fmaf(y4.z, wb[2], va[t]);
            va[t] = fmaf(y4.w, wb[3], va[t]);
        }
    }

    const float bj = b1[j];
    for (int t = 0; t < 32; ++t) {
        int n = nbase + t;
        if (n < NN) {
            U [(size_t)n * COUT + j] = ua[t] + bj;
            Vv[(size_t)n * COUT + j] = va[t];
        }
    }
}

// ---------------------------------------------------------------------------
// W2 -> MFMA B-fragment prep (hi/lo bf16 split), fragment-packed layout.
// frag = nt*KS + ks; lane l holds W2[ks*32 + (l>>4)*8 + m][nt*16 + (l&15)],
// m=0..7, packed as 8 ushort at F[(frag*64+lane)*8].  (HW-verified round 4/5.)
// ---------------------------------------------------------------------------
template<int COUT>
__global__ void w2frag_prep(const float* __restrict__ W2,
                            unsigned short* __restrict__ Fhi,
                            unsigned short* __restrict__ Flo)
{
    constexpr int KS = COUT / 32;
    constexpr int NT = COUT / 16;
    int t = blockIdx.x * 256 + threadIdx.x;
    if (t >= NT * KS * 64) return;
    int frag = t >> 6, lane = t & 63;
    int ks = frag % KS, nt = frag / KS;
    int col = nt * 16 + (lane & 15);
    int k0 = ks * 32 + (lane >> 4) * 8;
    unsigned short h8[8], l8[8];
    #pragma unroll
    for (int m = 0; m < 8; ++m) {
        float w = W2[(size_t)(k0 + m) * COUT + col];
        __bf16 hb = (__bf16)w;
        float hf = (float)hb;
        __bf16 lb = (__bf16)(w - hf);
        h8[m] = __builtin_bit_cast(unsigned short, hb);
        l8[m] = __builtin_bit_cast(unsigned short, lb);
    }
    size_t base = (size_t)t * 8;
    #pragma unroll
    for (int m = 0; m < 8; ++m) { Fhi[base + m] = h8[m]; Flo[base + m] = l8[m]; }
}

// ---------------------------------------------------------------------------
// MFMA edge kernel, direct-gather A, 32-edge tiles (2 MFMA passes share each
// B-fragment LDS read -> halves the binding LDS traffic). One wave per node.
// Lane role: arow = lane&15 (edge row), akc = lane>>4 (k-chunk of K=32 step).
// t = relu(u+v) built & bf16 hi/lo split in REGISTERS (no t LDS). B hi+lo
// streamed from LDS (frag-packed, lane-contiguous b128, conflict-free).
// 512 thr = 8 nodes/block; launch_bounds (512,2): VGPR cap 256 -> NO SPILLS
// (round-5 lesson: cap 128 spilled ~5.5 GB/dispatch to scratch).
// ---------------------------------------------------------------------------
static __device__ __forceinline__ void split8(const float* t, bf16x8& hi, bf16x8& lo) {
    u16x8 h, l;
    #pragma unroll
    for (int i = 0; i < 8; ++i) {
        __bf16 hb = (__bf16)t[i];
        float hf = (float)hb;
        __bf16 lb = (__bf16)(t[i] - hf);
        h[i] = __builtin_bit_cast(unsigned short, hb);
        l[i] = __builtin_bit_cast(unsigned short, lb);
    }
    hi = __builtin_bit_cast(bf16x8, h);
    lo = __builtin_bit_cast(bf16x8, l);
}

template<int COUT>
__global__ void __launch_bounds__(512, 2) edge_node_mfma(
    const float* __restrict__ U, const float* __restrict__ Vv,
    const int* __restrict__ s_src, const int* __restrict__ row_off,
    const unsigned short* __restrict__ Fhi, const unsigned short* __restrict__ Flo,
    float* __restrict__ agg)
{
    constexpr int KS = COUT / 32;          // MFMA K-steps (4 / 2)
    constexpr int NT = COUT / 16;          // output col tiles (8 / 4)
    constexpr int NFRAG = KS * NT;

    __shared__ unsigned short w2hi[NFRAG * 512];
    __shared__ unsigned short w2lo[NFRAG * 512];

    const int tid = threadIdx.x;
    for (int i = tid; i < NFRAG * 64; i += 512) {
        *reinterpret_cast<u16x8*>(&w2hi[i * 8]) =
            *reinterpret_cast<const u16x8*>(&Fhi[(size_t)i * 8]);
        *reinterpret_cast<u16x8*>(&w2lo[i * 8]) =
            *reinterpret_cast<const u16x8*>(&Flo[(size_t)i * 8]);
    }
    __syncthreads();   // no block syncs after this

    const int wave = tid >> 6, lane = tid & 63;
    const int arow = lane & 15;            // A row (edge within 16-row pass)
    const int akc  = lane >> 4;            // k-chunk within K-step

    const int n = blockIdx.x * 8 + wave;   // grid = NN/8 exactly
    const int off0 = row_off[n];
    const int deg  = row_off[n + 1] - off0;

    // U chunks this lane needs (register-resident, per node)
    float4 ua[KS], ub[KS];
    #pragma unroll
    for (int ks = 0; ks < KS; ++ks) {
        const float* up = &U[(size_t)n * COUT + (size_t)(ks * 4 + akc) * 8];
        ua[ks] = *reinterpret_cast<const float4*>(up);
        ub[ks] = *reinterpret_cast<const float4*>(up + 4);
    }

    float nmax[NT];
    #pragma unroll
    for (int nt = 0; nt < NT; ++nt) nmax[nt] = -INFINITY;

    int pb = 0;
    // ---- double-pass tiles: 32 edges, B frags read once for both passes ----
    for (; pb + 16 < deg; pb += 32) {
        const bool v0 = (pb + arow) < deg;          // always true here
        const bool v1 = (pb + 16 + arow) < deg;
        const int s0 = v0 ? s_src[off0 + pb + arow] : 0;
        const int s1 = v1 ? s_src[off0 + pb + 16 + arow] : 0;
        const float* vr0 = &Vv[(size_t)s0 * COUT];
        const float* vr1 = &Vv[(size_t)s1 * COUT];
        const float m0 = v0 ? 1.f : 0.f;
        const float m1 = v1 ? 1.f : 0.f;

        f32x4 acc0[NT], acc1[NT];
        #pragma unroll
        for (int nt = 0; nt < NT; ++nt) {
            acc0[nt] = f32x4{0.f, 0.f, 0.f, 0.f};
            acc1[nt] = f32x4{0.f, 0.f, 0.f, 0.f};
        }

        #pragma unroll
        for (int ks = 0; ks < KS; ++ks) {
            const size_t kof = (size_t)(ks * 4 + akc) * 8;
            float4 va0 = *reinterpret_cast<const float4*>(vr0 + kof);
            float4 vb0 = *reinterpret_cast<const float4*>(vr0 + kof + 4);
            float4 va1 = *reinterpret_cast<const float4*>(vr1 + kof);
            float4 vb1 = *reinterpret_cast<const float4*>(vr1 + kof + 4);

            float t8[8];
            t8[0] = m0 * fmaxf(ua[ks].x + va0.x, 0.f);
            t8[1] = m0 * fmaxf(ua[ks].y + va0.y, 0.f);
            t8[2] = m0 * fmaxf(ua[ks].z + va0.z, 0.f);
            t8[3] = m0 * fmaxf(ua[ks].w + va0.w, 0.f);
            t8[4] = m0 * fmaxf(ub[ks].x + vb0.x, 0.f);
            t8[5] = m0 * fmaxf(ub[ks].y + vb0.y, 0.f);
            t8[6] = m0 * fmaxf(ub[ks].z + vb0.z, 0.f);
            t8[7] = m0 * fmaxf(ub[ks].w + vb0.w, 0.f);
            bf16x8 ahi0, alo0;
            split8(t8, ahi0, alo0);

            t8[0] = m1 * fmaxf(ua[ks].x + va1.x, 0.f);
            t8[1] = m1 * fmaxf(ua[ks].y + va1.y, 0.f);
            t8[2] = m1 * fmaxf(ua[ks].z + va1.z, 0.f);
            t8[3] = m1 * fmaxf(ua[ks].w + va1.w, 0.f);
            t8[4] = m1 * fmaxf(ub[ks].x + vb1.x, 0.f);
            t8[5] = m1 * fmaxf(ub[ks].y + vb1.y, 0.f);
            t8[6] = m1 * fmaxf(ub[ks].z + vb1.z, 0.f);
            t8[7] = m1 * fmaxf(ub[ks].w + vb1.w, 0.f);
            bf16x8 ahi1, alo1;
            split8(t8, ahi1, alo1);

            #pragma unroll
            for (int nt = 0; nt < NT; ++nt) {
                const size_t fb = (size_t)((nt * KS + ks) * 64 + lane) * 8;
                bf16x8 bhi = __builtin_bit_cast(bf16x8,
                    *reinterpret_cast<const u16x8*>(&w2hi[fb]));
                bf16x8 blo = __builtin_bit_cast(bf16x8,
                    *reinterpret_cast<const u16x8*>(&w2lo[fb]));
                acc0[nt] = __builtin_amdgcn_mfma_f32_16x16x32_bf16(ahi0, bhi, acc0[nt], 0, 0, 0);
                acc0[nt] = __builtin_amdgcn_mfma_f32_16x16x32_bf16(ahi0, blo, acc0[nt], 0, 0, 0);
                acc0[nt] = __builtin_amdgcn_mfma_f32_16x16x32_bf16(alo0, bhi, acc0[nt], 0, 0, 0);
                acc1[nt] = __builtin_amdgcn_mfma_f32_16x16x32_bf16(ahi1, bhi, acc1[nt], 0, 0, 0);
                acc1[nt] = __builtin_amdgcn_mfma_f32_16x16x32_bf16(ahi1, blo, acc1[nt], 0, 0, 0);
                acc1[nt] = __builtin_amdgcn_mfma_f32_16x16x32_bf16(alo1, bhi, acc1[nt], 0, 0, 0);
            }
        }

        // masked max (D: row = akc*4 + r, col = nt*16 + (lane&15))
        #pragma unroll
        for (int nt = 0; nt < NT; ++nt) {
            float m4 = -INFINITY;
            #pragma unroll
            for (int r = 0; r < 4; ++r) {
                int e = akc * 4 + r;
                if (pb + e < deg)      m4 = fmaxf(m4, acc0[nt][r]);
                if (pb + 16 + e < deg) m4 = fmaxf(m4, acc1[nt][r]);
            }
            m4 = fmaxf(m4, __shfl_xor(m4, 16, 64));
            m4 = fmaxf(m4, __shfl_xor(m4, 32, 64));
            nmax[nt] = fmaxf(nmax[nt], m4);
        }
    }

    // ---- single-pass tail (<=16 remaining edges); deg wave-uniform ----
    if (pb < deg) {
        const bool v0 = (pb + arow) < deg;
        const int s0 = v0 ? s_src[off0 + pb + arow] : 0;
        const float* vr0 = &Vv[(size_t)s0 * COUT];
        const float m0 = v0 ? 1.f : 0.f;

        f32x4 acc0[NT];
        #pragma unroll
        for (int nt = 0; nt < NT; ++nt) acc0[nt] = f32x4{0.f, 0.f, 0.f, 0.f};

        #pragma unroll
        for (int ks = 0; ks < KS; ++ks) {
            const size_t kof = (size_t)(ks * 4 + akc) * 8;
            float4 va0 = *reinterpret_cast<const float4*>(vr0 + kof);
            float4 vb0 = *reinterpret_cast<const float4*>(vr0 + kof + 4);
            float t8[8];
            t8[0] = m0 * fmaxf(ua[ks].x + va0.x, 0.f);
            t8[1] = m0 * fmaxf(ua[ks].y + va0.y, 0.f);
            t8[2] = m0 * fmaxf(ua[ks].z + va0.z, 0.f);
            t8[3] = m0 * fmaxf(ua[ks].w + va0.w, 0.f);
            t8[4] = m0 * fmaxf(ub[ks].x + vb0.x, 0.f);
            t8[5] = m0 * fmaxf(ub[ks].y + vb0.y, 0.f);
            t8[6] = m0 * fmaxf(ub[ks].z + vb0.z, 0.f);
            t8[7] = m0 * fmaxf(ub[ks].w + vb0.w, 0.f);
            bf16x8 ahi0, alo0;
            split8(t8, ahi0, alo0);

            #pragma unroll
            for (int nt = 0; nt < NT; ++nt) {
                const size_t fb = (size_t)((nt * KS + ks) * 64 + lane) * 8;
                bf16x8 bhi = __builtin_bit_cast(bf16x8,
                    *reinterpret_cast<const u16x8*>(&w2hi[fb]));
                bf16x8 blo = __builtin_bit_cast(bf16x8,
                    *reinterpret_cast<const u16x8*>(&w2lo[fb]));
                acc0[nt] = __builtin_amdgcn_mfma_f32_16x16x32_bf16(ahi0, bhi, acc0[nt], 0, 0, 0);
                acc0[nt] = __builtin_amdgcn_mfma_f32_16x16x32_bf16(ahi0, blo, acc0[nt], 0, 0, 0);
                acc0[nt] = __builtin_amdgcn_mfma_f32_16x16x32_bf16(alo0, bhi, acc0[nt], 0, 0, 0);
            }
        }

        #pragma unroll
        for (int nt = 0; nt < NT; ++nt) {
            float m4 = -INFINITY;
            #pragma unroll
            for (int r = 0; r < 4; ++r) {
                int e = akc * 4 + r;
                if (pb + e < deg) m4 = fmaxf(m4, acc0[nt][r]);
            }
            m4 = fmaxf(m4, __shfl_xor(m4, 16, 64));
            m4 = fmaxf(m4, __shfl_xor(m4, 32, 64));
            nmax[nt] = fmaxf(nmax[nt], m4);
        }
    }

    // direct store; deg==0 leaves -inf sentinel
    if (lane < 16) {
        #pragma unroll
        for (int nt = 0; nt < NT; ++nt)
            agg[(size_t)n * COUT + nt * 16 + lane] = nmax[nt];
    }
}

__global__ void finalize_k(const float* __restrict__ agg,
                           const float* __restrict__ b2,
                           float* __restrict__ out) {
    int i = blockIdx.x * 256 + threadIdx.x;
    if (i < NN * 128) {
        float a = agg[i];
        out[i] = (a == -INFINITY) ? 0.f : a + b2[i & 127];
    }
}

// ---------------------------------------------------------------------------
extern "C" void kernel_launch(void* const* d_in, const int* in_sizes, int n_in,
                              void* d_out, int out_size, void* d_ws, size_t ws_size,
                              hipStream_t stream)
{
    const float* x  = (const float*)d_in[0];
    const int*   ei = (const int*)d_in[1];
    const int* src = ei;          // edge_index[0]
    const int* dst = ei + NE;     // edge_index[1]

    const float *W1[4], *B1[4], *W2[4], *B2[4];
    for (int i = 0; i < 4; ++i) {
        W1[i] = (const float*)d_in[2 + 4 * i];
        B1[i] = (const float*)d_in[3 + 4 * i];
        W2[i] = (const float*)d_in[4 + 4 * i];
        B2[i] = (const float*)d_in[5 + 4 * i];
    }

    float* U   = (float*)d_ws;
    float* V   = U   + (size_t)NN * 128;
    float* agg = V   + (size_t)NN * 128;
    int* row_off = (int*)(agg + (size_t)NN * 128);   // NN+16 ints (padded)
    int* cnt     = row_off + (NN + 16);              // NN+16 ints
    int* s_src   = cnt + (NN + 16);                  // NE ints
    unsigned short* fbase = (unsigned short*)(s_src + NE);
    unsigned short *FH[4], *FL[4];
    for (int i = 0; i < 4; ++i) {
        FH[i] = fbase + (size_t)i * 32768;
        FL[i] = FH[i] + 16384;
    }

    float* out = (float*)d_out;

    // ---- one-time CSR build ----
    (void)hipMemsetAsync(cnt, 0, (size_t)NN * sizeof(int), stream);
    hipLaunchKernelGGL(hist_k, dim3((NE + 255) / 256), dim3(256), 0, stream, dst, cnt);
    hipLaunchKernelGGL(scan_k, dim3(1), dim3(1024), 0, stream, cnt, row_off);
    hipLaunchKernelGGL(copy_k, dim3((NN + 255) / 256), dim3(256), 0, stream, row_off, cnt, NN);
    hipLaunchKernelGGL(scatter_k, dim3((NE + 255) / 256), dim3(256), 0, stream, src, dst, cnt, s_src);

    // ---- W2 fragment prep (hi/lo bf16 split), all 4 layers ----
    hipLaunchKernelGGL((w2frag_prep<64>),  dim3(2), dim3(256), 0, stream, W2[0], FH[0], FL[0]);
    hipLaunchKernelGGL((w2frag_prep<128>), dim3(8), dim3(256), 0, stream, W2[1], FH[1], FL[1]);
    hipLaunchKernelGGL((w2frag_prep<128>), dim3(8), dim3(256), 0, stream, W2[2], FH[2], FL[2]);
    hipLaunchKernelGGL((w2frag_prep<128>), dim3(8), dim3(256), 0, stream, W2[3], FH[3], FL[3]);

    const int nblkA = (NN + 31) / 32;
    const int nblkE = NN / 8;      // 6250

    // ---- layer 0: 32 -> 64 ----
    hipLaunchKernelGGL((node_transform<32, 64, true>), dim3(nblkA), dim3(64), 0, stream,
                       x, nullptr, nullptr, W1[0], B1[0], U, V);
    hipLaunchKernelGGL((edge_node_mfma<64>), dim3(nblkE), dim3(512), 0, stream,
                       U, V, s_src, row_off, FH[0], FL[0], agg);

    // ---- layer 1: 64 -> 128 ----
    hipLaunchKernelGGL((node_transform<64, 128, false>), dim3(nblkA), dim3(128), 0, stream,
                       nullptr, agg, B2[0], W1[1], B1[1], U, V);
    hipLaunchKernelGGL((edge_node_mfma<128>), dim3(nblkE), dim3(512), 0, stream,
                       U, V, s_src, row_off, FH[1], FL[1], agg);

    // ---- layer 2: 128 -> 128 ----
    hipLaunchKernelGGL((node_transform<128, 128, false>), dim3(nblkA), dim3(128), 0, stream,
                       nullptr, agg, B2[1], W1[2], B1[2], U, V);
    hipLaunchKernelGGL((edge_node_mfma<128>), dim3(nblkE), dim3(512), 0, stream,
                       U, V, s_src, row_off, FH[2], FL[2], agg);

    // ---- layer 3: 128 -> 128 ----
    hipLaunchKernelGGL((node_transform<128, 128, false>), dim3(nblkA), dim3(128), 0, stream,
                       nullptr, agg, B2[2], W1[3], B1[3], U, V);
    hipLaunchKernelGGL((edge_node_mfma<128>), dim3(nblkE), dim3(512), 0, stream,
                       U, V, s_src, row_off, FH[3], FL[3], agg);

    // ---- finalize: +b2_3, empty -> 0 ----
    hipLaunchKernelGGL(finalize_k, dim3((NN * 128 + 255) / 256), dim3(256), 0, stream,
                       agg, B2[3], out);
}